// Round 8
// baseline (366.704 us; speedup 1.0000x reference)
//
#include <hip/hip_runtime.h>
#include <hip/hip_bf16.h>
#include <math.h>

#define N_USERS 100000
#define N_ITEMS 50000
#define N_EDGES 2000000
#define D 64

// Segment-keyed bins: fwd bin = (d>>9)*8 + (s>>14)  [user segs of 16384 = 2 MB bf16]
//                     bwd bin = (s>>9)*4 + (d>>14)  [item segs of 16384 = 2 MB bf16]
#define SEG_SH 14
#define FSEG 8                       // slots (s>>14 in 0..6, slot 7 empty)
#define BSEG 4                       // slots (d>>14 in 0..3)
#define FB2 (98 * FSEG)              // 784
#define BB2 (196 * BSEG)             // 784
#define NB2 (FB2 + BB2)              // 1568
#define CHUNK 16384                  // edges per binfill WG (runs ~21 entries = 84 B)
#define NCHUNK ((N_EDGES + CHUNK - 1) / CHUNK)   // 123
#define FWD_WGS 782                  // ceil(50000/64)
#define BWD_WGS 1563                 // ceil(100000/64)
#define CAPC 1024                    // per-cell sorted capacity (mean ~420)

// ---- bf16 pack/unpack helpers --------------------------------------------
__device__ __forceinline__ float blo(unsigned u) {
    union { unsigned i; float f; } c; c.i = u << 16; return c.f;
}
__device__ __forceinline__ float bhi(unsigned u) {
    union { unsigned i; float f; } c; c.i = u & 0xFFFF0000u; return c.f;
}
__device__ __forceinline__ unsigned bpack(float x, float y) {
    __hip_bfloat16 a = __float2bfloat16(x), b = __float2bfloat16(y);
    unsigned short ua = *reinterpret_cast<unsigned short*>(&a);
    unsigned short ub = *reinterpret_cast<unsigned short*>(&b);
    return (unsigned)ua | ((unsigned)ub << 16);
}

// ---------------------------------------------------------------------------
// Convert h_user fp32 -> packed bf16 pairs (hu16): one uint = features 2q,2q+1.
// ---------------------------------------------------------------------------
__global__ __launch_bounds__(256) void h2b_kernel(
    const float2* __restrict__ in, unsigned* __restrict__ out, int n) {
    int stride = gridDim.x * blockDim.x;
    for (int i = blockIdx.x * blockDim.x + threadIdx.x; i < n; i += stride) {
        float2 v = in[i];
        out[i] = bpack(v.x, v.y);
    }
}

// ---------------------------------------------------------------------------
// Histogram of segment-keyed bin sizes (1568 bins, LDS-staged).
// ---------------------------------------------------------------------------
__global__ __launch_bounds__(256) void hist_kernel(
    const int* __restrict__ src, const int* __restrict__ dst, int* __restrict__ gh) {
    __shared__ int h[NB2];
    for (int i = threadIdx.x; i < NB2; i += 256) h[i] = 0;
    __syncthreads();
    int stride = gridDim.x * blockDim.x;
    for (int e = blockIdx.x * blockDim.x + threadIdx.x; e < N_EDGES; e += stride) {
        int s = src[e], d = dst[e];
        atomicAdd(&h[(d >> 9) * FSEG + (s >> SEG_SH)], 1);
        atomicAdd(&h[FB2 + (s >> 9) * BSEG + (d >> SEG_SH)], 1);
    }
    __syncthreads();
    for (int i = threadIdx.x; i < NB2; i += 256) {
        int v = h[i];
        if (v) atomicAdd(&gh[i], v);
    }
}

// ---------------------------------------------------------------------------
// Single-block exclusive scan; also initializes the running cursor array.
// ---------------------------------------------------------------------------
__global__ void scan_excl(const int* __restrict__ in, int* __restrict__ out,
                          int* __restrict__ cur, int n) {
    const int T = 1024, E = 4;
    __shared__ int wsum[16];
    __shared__ int s_carry;
    if (threadIdx.x == 0) s_carry = 0;
    __syncthreads();

    int lane = threadIdx.x & 63;
    int wid  = threadIdx.x >> 6;

    for (int base = 0; base < n; base += T * E) {
        int idx0 = base + threadIdx.x * E;
        int v[E];
        int tot = 0;
#pragma unroll
        for (int e = 0; e < E; e++) {
            int i = idx0 + e;
            v[e] = (i < n) ? in[i] : 0;
            tot += v[e];
        }
        int incl = tot;
#pragma unroll
        for (int off = 1; off < 64; off <<= 1) {
            int t = __shfl_up(incl, off);
            if (lane >= off) incl += t;
        }
        if (lane == 63) wsum[wid] = incl;
        __syncthreads();
        if (wid == 0 && lane < 16) {
            int t = wsum[lane];
            int sc = t;
#pragma unroll
            for (int off = 1; off < 16; off <<= 1) {
                int u = __shfl_up(sc, off);
                if (lane >= off) sc += u;
            }
            wsum[lane] = sc - t;
        }
        __syncthreads();
        int wave_off = wsum[wid];
        int excl = s_carry + wave_off + incl - tot;
#pragma unroll
        for (int e = 0; e < E; e++) {
            int i = idx0 + e;
            if (i < n) { out[i] = excl; cur[i] = excl; }
            excl += v[e];
        }
        __syncthreads();
        if (threadIdx.x == T - 1) s_carry += wave_off + incl;
        __syncthreads();
    }
    if (threadIdx.x == 0) out[n] = s_carry;
}

// ---------------------------------------------------------------------------
// binfill: two-scan chunk-aggregated scatter over 1568 bins. CHUNK=16384 keeps
// per-(chunk,bin) runs ~21 entries (~84 B >= line) despite the finer bins.
// fwd entry: s(17b) | d_local9<<17 ; bwd entry: d(16b) | s_local9<<16.
// ---------------------------------------------------------------------------
__global__ __launch_bounds__(256) void binfill_kernel(
    const int* __restrict__ src, const int* __restrict__ dst,
    int* __restrict__ gcur, unsigned* __restrict__ stage) {
    __shared__ int cnt[NB2];
    __shared__ int gbase[NB2];
    __shared__ int lcur[NB2];
    int base = blockIdx.x * CHUNK;
    int nE = N_EDGES - base; if (nE > CHUNK) nE = CHUNK;

    for (int t = threadIdx.x; t < NB2; t += 256) { cnt[t] = 0; lcur[t] = 0; }
    __syncthreads();

    for (int k = threadIdx.x; k < nE; k += 256) {
        int s = src[base + k], d = dst[base + k];
        atomicAdd(&cnt[(d >> 9) * FSEG + (s >> SEG_SH)], 1);
        atomicAdd(&cnt[FB2 + (s >> 9) * BSEG + (d >> SEG_SH)], 1);
    }
    __syncthreads();
    for (int t = threadIdx.x; t < NB2; t += 256) {
        int cv = cnt[t];
        gbase[t] = cv ? atomicAdd(&gcur[t], cv) : 0;
    }
    __syncthreads();
    for (int k = threadIdx.x; k < nE; k += 256) {
        int s = src[base + k], d = dst[base + k];
        int bf = (d >> 9) * FSEG + (s >> SEG_SH);
        int p = atomicAdd(&lcur[bf], 1);
        stage[gbase[bf] + p] = (unsigned)s | ((unsigned)(d & 511) << 17);
        int bb = FB2 + (s >> 9) * BSEG + (d >> SEG_SH);
        int q2 = atomicAdd(&lcur[bb], 1);
        stage[gbase[bb] + q2] = (unsigned)d | ((unsigned)(s & 511) << 16);
    }
}

// ---------------------------------------------------------------------------
// Global softmax stats over edge_w[N_ITEMS]: stats[0]=max, stats[1]=sum(exp(x-max))
// ---------------------------------------------------------------------------
__global__ void softmax_stats_kernel(const float* __restrict__ w, float* __restrict__ stats) {
    __shared__ float red[16];
    int tid = threadIdx.x, lane = tid & 63, wid = tid >> 6;

    float m = -INFINITY;
    for (int i = tid; i < N_ITEMS; i += 1024) m = fmaxf(m, w[i]);
#pragma unroll
    for (int off = 32; off; off >>= 1) m = fmaxf(m, __shfl_xor(m, off));
    if (lane == 0) red[wid] = m;
    __syncthreads();
    if (tid == 0) {
        float t = red[0];
        for (int k = 1; k < 16; k++) t = fmaxf(t, red[k]);
        red[0] = t;
    }
    __syncthreads();
    m = red[0];
    __syncthreads();

    float s = 0.f;
    for (int i = tid; i < N_ITEMS; i += 1024) s += expf(w[i] - m);
#pragma unroll
    for (int off = 32; off; off >>= 1) s += __shfl_xor(s, off);
    if (lane == 0) red[wid] = s;
    __syncthreads();
    if (tid == 0) {
        float t = 0.f;
        for (int k = 0; k < 16; k++) t += red[k];
        stats[0] = m;
        stats[1] = t;
    }
}

// ---------------------------------------------------------------------------
// pass2 fwd: one 512-thread WG per 64 items, SEGMENT-OUTER: for each of 8
// user segments (2 MB bf16 window), counting-sort that cell's entries, gather
// from the L2-resident window, accumulate into per-item VGPR accumulators.
// All WGs sweep segments in phase (bucket-size sigma ~2%).
// ---------------------------------------------------------------------------
__global__ __launch_bounds__(512) void pass2_fwd_kernel(
    const unsigned* __restrict__ hu16, const float* __restrict__ pf,
    const float* __restrict__ edge_w, const unsigned* __restrict__ stage,
    const int* __restrict__ binoff, const float* __restrict__ stats,
    unsigned* __restrict__ rst16) {
    __shared__ int cnt[64];
    __shared__ int loc[65];
    __shared__ int lcur[64];
    __shared__ int sorted[CAPC];
    int r = blockIdx.x;
    int B = r >> 3, sub = r & 7;
    int tid = threadIdx.x, lane = tid & 63, wv = tid >> 6;
    int q = lane & 31, half = lane >> 5;

    float ax[8], ay[8];
    int dg[8];
#pragma unroll
    for (int j = 0; j < 8; j++) { ax[j] = 0.f; ay[j] = 0.f; dg[j] = 0; }

    for (int seg = 0; seg < FSEG; seg++) {
        int cbeg = binoff[B * FSEG + seg], cend = binoff[B * FSEG + seg + 1];
        if (cbeg == cend) continue;    // uniform branch (cell bounds are WG-wide)
        if (tid < 64) { cnt[tid] = 0; lcur[tid] = 0; }
        __syncthreads();
        for (int k = cbeg + tid; k < cend; k += 512) {
            unsigned e = stage[k];
            if ((int)(e >> 23) == sub) atomicAdd(&cnt[(e >> 17) & 63], 1);
        }
        __syncthreads();
        if (tid < 64) {
            int v = cnt[tid];
            int incl = v;
#pragma unroll
            for (int off = 1; off < 64; off <<= 1) {
                int t = __shfl_up(incl, off);
                if (tid >= off) incl += t;
            }
            loc[tid] = incl - v;
            if (tid == 63) loc[64] = incl;
        }
        __syncthreads();
        int nf = loc[64];

        if (nf <= CAPC) {
            for (int k = cbeg + tid; k < cend; k += 512) {
                unsigned e = stage[k];
                if ((int)(e >> 23) == sub) {
                    int il = (e >> 17) & 63;
                    int p = atomicAdd(&lcur[il], 1);
                    sorted[loc[il] + p] = (int)(e & 0x1FFFFu);
                }
            }
            __syncthreads();
#pragma unroll
            for (int j = 0; j < 8; j++) {
                int il = wv + 8 * j;
                int a = loc[il], b = loc[il + 1];
                dg[j] += b - a;
                int k = a;
                for (; k + 4 <= b; k += 4) {
                    int s0 = sorted[k + half], s1 = sorted[k + 2 + half];
                    unsigned u0 = hu16[(s0 << 5) + q];
                    unsigned u1 = hu16[(s1 << 5) + q];
                    ax[j] += blo(u0) + blo(u1);
                    ay[j] += bhi(u0) + bhi(u1);
                }
                for (; k + 2 <= b; k += 2) {
                    unsigned u = hu16[(sorted[k + half] << 5) + q];
                    ax[j] += blo(u); ay[j] += bhi(u);
                }
                if (k < b && half == 0) {
                    unsigned u = hu16[(sorted[k] << 5) + q];
                    ax[j] += blo(u); ay[j] += bhi(u);
                }
            }
            __syncthreads();   // protect cnt/loc/sorted before next cell
        } else {
            // overflow fallback (statistically unreachable): direct cell scan
#pragma unroll
            for (int j = 0; j < 8; j++) {
                int il = wv + 8 * j;
                unsigned want = ((unsigned)sub << 6) | (unsigned)il;
                for (int k = cbeg; k < cend; k++) {
                    unsigned e = stage[k];
                    if ((e >> 17) == want) {
                        dg[j]++;
                        if (half == 0) {
                            unsigned u = hu16[((e & 0x1FFFFu) << 5) + q];
                            ax[j] += blo(u); ay[j] += bhi(u);
                        }
                    }
                }
            }
            __syncthreads();
        }
    }

    float m = stats[0], ssum = stats[1];
    const float2* PF2 = (const float2*)pf;
#pragma unroll
    for (int j = 0; j < 8; j++) {
        int il = wv + 8 * j;
        int i = r * 64 + il;
        if (i >= N_ITEMS) continue;
        ax[j] += __shfl_xor(ax[j], 32);
        ay[j] += __shfl_xor(ay[j], 32);
        if (half == 0) {
            float deg = (float)dg[j];
            if (deg < 1.f) deg = 1.f;
            float sc = expf(edge_w[i] - m) / (ssum * deg);
            float2 pv = PF2[(size_t)i * 32 + q];
            float vx = (ax[j] + 0.5f * tanhf(pv.x)) * sc;
            float vy = (ay[j] + 0.5f * tanhf(pv.y)) * sc;
            rst16[(size_t)i * 32 + q] = bpack(vx, vy);
        }
    }
}

// ---------------------------------------------------------------------------
// pass2 bwd: one 512-thread WG per 64 users; segment-outer over 4 item
// segments of rst16 (2 MB windows); per-user VGPR accumulators.
// ---------------------------------------------------------------------------
__global__ __launch_bounds__(512) void pass2_bwd_kernel(
    const unsigned* __restrict__ rst16, const unsigned* __restrict__ stage,
    const int* __restrict__ binoff, float* __restrict__ out) {
    __shared__ int cnt[64];
    __shared__ int loc[65];
    __shared__ int lcur[64];
    __shared__ int sorted[CAPC];
    int r = blockIdx.x;
    int B = r >> 3, sub = r & 7;
    int tid = threadIdx.x, lane = tid & 63, wv = tid >> 6;
    int q = lane & 31, half = lane >> 5;

    float ax[8], ay[8];
    int dg[8];
#pragma unroll
    for (int j = 0; j < 8; j++) { ax[j] = 0.f; ay[j] = 0.f; dg[j] = 0; }

    for (int seg = 0; seg < BSEG; seg++) {
        int cbeg = binoff[FB2 + B * BSEG + seg], cend = binoff[FB2 + B * BSEG + seg + 1];
        if (cbeg == cend) continue;
        if (tid < 64) { cnt[tid] = 0; lcur[tid] = 0; }
        __syncthreads();
        for (int k = cbeg + tid; k < cend; k += 512) {
            unsigned e = stage[k];
            if ((int)(e >> 22) == sub) atomicAdd(&cnt[(e >> 16) & 63], 1);
        }
        __syncthreads();
        if (tid < 64) {
            int v = cnt[tid];
            int incl = v;
#pragma unroll
            for (int off = 1; off < 64; off <<= 1) {
                int t = __shfl_up(incl, off);
                if (tid >= off) incl += t;
            }
            loc[tid] = incl - v;
            if (tid == 63) loc[64] = incl;
        }
        __syncthreads();
        int nf = loc[64];

        if (nf <= CAPC) {
            for (int k = cbeg + tid; k < cend; k += 512) {
                unsigned e = stage[k];
                if ((int)(e >> 22) == sub) {
                    int il = (e >> 16) & 63;
                    int p = atomicAdd(&lcur[il], 1);
                    sorted[loc[il] + p] = (int)(e & 0xFFFFu);
                }
            }
            __syncthreads();
#pragma unroll
            for (int j = 0; j < 8; j++) {
                int il = wv + 8 * j;
                int a = loc[il], b = loc[il + 1];
                dg[j] += b - a;
                int k = a;
                for (; k + 4 <= b; k += 4) {
                    int d0 = sorted[k + half], d1 = sorted[k + 2 + half];
                    unsigned u0 = rst16[(d0 << 5) + q];
                    unsigned u1 = rst16[(d1 << 5) + q];
                    ax[j] += blo(u0) + blo(u1);
                    ay[j] += bhi(u0) + bhi(u1);
                }
                for (; k + 2 <= b; k += 2) {
                    unsigned u = rst16[(sorted[k + half] << 5) + q];
                    ax[j] += blo(u); ay[j] += bhi(u);
                }
                if (k < b && half == 0) {
                    unsigned u = rst16[(sorted[k] << 5) + q];
                    ax[j] += blo(u); ay[j] += bhi(u);
                }
            }
            __syncthreads();
        } else {
#pragma unroll
            for (int j = 0; j < 8; j++) {
                int il = wv + 8 * j;
                unsigned want = ((unsigned)sub << 6) | (unsigned)il;
                for (int k = cbeg; k < cend; k++) {
                    unsigned e = stage[k];
                    if ((e >> 16) == want) {
                        dg[j]++;
                        if (half == 0) {
                            unsigned u = rst16[((e & 0xFFFFu) << 5) + q];
                            ax[j] += blo(u); ay[j] += bhi(u);
                        }
                    }
                }
            }
            __syncthreads();
        }
    }

    float2* OUT2 = (float2*)out;
#pragma unroll
    for (int j = 0; j < 8; j++) {
        int il = wv + 8 * j;
        int u = r * 64 + il;
        if (u >= N_USERS) continue;
        ax[j] += __shfl_xor(ax[j], 32);
        ay[j] += __shfl_xor(ay[j], 32);
        if (half == 0) {
            float deg = (float)dg[j];
            if (deg < 1.f) deg = 1.f;
            OUT2[(size_t)u * 32 + q] = make_float2(ax[j] / deg, ay[j] / deg);
        }
    }
}

// ---------------------------------------------------------------------------
extern "C" void kernel_launch(void* const* d_in, const int* in_sizes, int n_in,
                              void* d_out, int out_size, void* d_ws, size_t ws_size,
                              hipStream_t stream) {
    const float* h_user = (const float*)d_in[0];   // [N_USERS, D]
    const float* pf     = (const float*)d_in[1];   // [N_ITEMS, D]
    const float* edge_w = (const float*)d_in[2];   // [N_ITEMS]
    const int*   src    = (const int*)d_in[3];     // [N_EDGES]
    const int*   dst    = (const int*)d_in[4];     // [N_EDGES]
    float* out = (float*)d_out;                    // [N_USERS, D]

    // workspace carve-up (~35.3 MB)
    char* p = (char*)d_ws;
    int* gh     = (int*)p;      p += sizeof(int) * NB2;
    int* binoff = (int*)p;      p += sizeof(int) * (NB2 + 1);
    int* gcur   = (int*)p;      p += sizeof(int) * NB2;
    unsigned* stage = (unsigned*)p; p += sizeof(unsigned) * (size_t)2 * N_EDGES;
    unsigned* hu16  = (unsigned*)p; p += sizeof(unsigned) * (size_t)N_USERS * 32;
    unsigned* rst16 = (unsigned*)p; p += sizeof(unsigned) * (size_t)N_ITEMS * 32;
    float* stats = (float*)p;   p += 2 * sizeof(float);

    hipMemsetAsync(gh, 0, sizeof(int) * NB2, stream);

    hist_kernel<<<256, 256, 0, stream>>>(src, dst, gh);
    scan_excl<<<1, 1024, 0, stream>>>(gh, binoff, gcur, NB2);
    binfill_kernel<<<NCHUNK, 256, 0, stream>>>(src, dst, gcur, stage);
    h2b_kernel<<<1024, 256, 0, stream>>>((const float2*)h_user, hu16, N_USERS * 32);
    softmax_stats_kernel<<<1, 1024, 0, stream>>>(edge_w, stats);
    pass2_fwd_kernel<<<FWD_WGS, 512, 0, stream>>>(hu16, pf, edge_w, stage, binoff, stats, rst16);
    pass2_bwd_kernel<<<BWD_WGS, 512, 0, stream>>>(rst16, stage, binoff, out);
}